// Round 1
// baseline (10819.653 us; speedup 1.0000x reference)
//
#include <hip/hip_runtime.h>
#include <hip/hip_bf16.h>

#define N_NODES 100000
#define N_EDGES 3200000
#define D 256

typedef __attribute__((ext_vector_type(8))) short short8;   // 8 bf16 (4 VGPRs)
typedef __attribute__((ext_vector_type(4))) float floatx4;  // MFMA C/D

__device__ __forceinline__ unsigned short f32_to_bf16_rne(float f) {
    unsigned int u = __float_as_uint(f);
    u += 0x7FFFu + ((u >> 16) & 1u);   // round-to-nearest-even
    return (unsigned short)(u >> 16);
}

// ---------------- zero-init output (atomics accumulate into it) --------------
__global__ __launch_bounds__(256) void zero_out_k(float* __restrict__ out) {
    size_t i = (size_t)blockIdx.x * 256 + threadIdx.x;
    ((float4*)out)[i] = make_float4(0.f, 0.f, 0.f, 0.f);
}

// ---------------- W (fp32 [K=256][N=256]) -> bf16, MFMA-B-fragment order -----
// layout: t = ((ntile*8 + kstep)*64 + lane)*8 + j
//   value = W[k = kstep*32 + (lane>>4)*8 + j][n = ntile*16 + (lane&15)]
__global__ __launch_bounds__(256) void convert_w_k(const float* __restrict__ w,
                                                   unsigned short* __restrict__ wsw) {
    int t = blockIdx.x * 256 + threadIdx.x;      // 0..65535
    int j     = t & 7;
    int lane  = (t >> 3) & 63;
    int kstep = (t >> 9) & 7;
    int ntile = t >> 12;
    int k = kstep * 32 + (lane >> 4) * 8 + j;
    int n = ntile * 16 + (lane & 15);
    wsw[t] = f32_to_bf16_rne(w[k * D + n]);
}

// ---------------- xw = x @ W, bf16 MFMA 16x16x32 -----------------------------
// block = 256 thr = 4 waves; each wave: 16 rows x 256 cols (16 n-tiles).
// W fragments staged in LDS (128 KiB), each frag load = 1 ds_read_b128.
__global__ __launch_bounds__(256) void gemm_xw_k(const float* __restrict__ x,
                                                 const unsigned short* __restrict__ wsw,
                                                 float* __restrict__ xw) {
    __shared__ uint4 wlds[8192];  // 128 KiB swizzled bf16 W
    const int tid = threadIdx.x;
#pragma unroll
    for (int i = 0; i < 32; ++i) {
        int idx = i * 256 + tid;
        wlds[idx] = ((const uint4*)wsw)[idx];
    }
    __syncthreads();

    const int lane = tid & 63;
    const int wave = tid >> 6;
    const int q    = lane >> 4;
    const int ml   = lane & 15;
    const long rowBase = (long)blockIdx.x * 64 + wave * 16;
    long arow = rowBase + ml;            // row this lane loads for the A frag
    if (arow >= N_NODES) arow = 0;       // clamp; stores masked below
    const float* xr = x + arow * (long)D;

    floatx4 acc[16];
#pragma unroll
    for (int i = 0; i < 16; ++i) acc[i] = (floatx4){0.f, 0.f, 0.f, 0.f};

    const short8* wfrag = (const short8*)wlds;

#pragma unroll
    for (int ks = 0; ks < 8; ++ks) {
        // A frag: x[arow][ks*32 + q*8 + 0..7], fp32 -> bf16
        const float4 a0 = *(const float4*)(xr + ks * 32 + q * 8);
        const float4 a1 = *(const float4*)(xr + ks * 32 + q * 8 + 4);
        short8 af;
        af[0] = (short)f32_to_bf16_rne(a0.x);
        af[1] = (short)f32_to_bf16_rne(a0.y);
        af[2] = (short)f32_to_bf16_rne(a0.z);
        af[3] = (short)f32_to_bf16_rne(a0.w);
        af[4] = (short)f32_to_bf16_rne(a1.x);
        af[5] = (short)f32_to_bf16_rne(a1.y);
        af[6] = (short)f32_to_bf16_rne(a1.z);
        af[7] = (short)f32_to_bf16_rne(a1.w);
#pragma unroll
        for (int nt = 0; nt < 16; ++nt) {
            acc[nt] = __builtin_amdgcn_mfma_f32_16x16x32_bf16(
                af, wfrag[(nt * 8 + ks) * 64 + lane], acc[nt], 0, 0, 0);
        }
    }

    // C/D layout: col = nt*16 + (lane&15), row = rowBase + q*4 + r
#pragma unroll
    for (int nt = 0; nt < 16; ++nt) {
#pragma unroll
        for (int r = 0; r < 4; ++r) {
            long orow = rowBase + q * 4 + r;
            if (orow < N_NODES)
                xw[orow * (long)D + nt * 16 + ml] = acc[nt][r];
        }
    }
}

// ---------------- scatter: out[r] += v * xw[c], one wave per edge ------------
__global__ __launch_bounds__(256) void scatter_k(const float* __restrict__ xw,
                                                 const int* __restrict__ erow,
                                                 const int* __restrict__ ecol,
                                                 const float* __restrict__ eval,
                                                 float* __restrict__ out) {
    const int e = blockIdx.x * 4 + (threadIdx.x >> 6);
    if (e >= N_EDGES) return;
    const int lane = threadIdx.x & 63;
    const int r = erow[e];
    const int c = ecol[e];
    const float v = eval[e];
    const float4 m = ((const float4*)(xw + (long)c * D))[lane];  // 1 KiB/row, coalesced
    float* dst = out + (long)r * D + lane * 4;
    atomicAdd(dst + 0, v * m.x);
    atomicAdd(dst + 1, v * m.y);
    atomicAdd(dst + 2, v * m.z);
    atomicAdd(dst + 3, v * m.w);
}

// ---------------- relu in place ----------------------------------------------
__global__ __launch_bounds__(256) void relu_k(float* __restrict__ out) {
    size_t i = (size_t)blockIdx.x * 256 + threadIdx.x;
    float4 v = ((float4*)out)[i];
    v.x = fmaxf(v.x, 0.f);
    v.y = fmaxf(v.y, 0.f);
    v.z = fmaxf(v.z, 0.f);
    v.w = fmaxf(v.w, 0.f);
    ((float4*)out)[i] = v;
}

extern "C" void kernel_launch(void* const* d_in, const int* in_sizes, int n_in,
                              void* d_out, int out_size, void* d_ws, size_t ws_size,
                              hipStream_t stream) {
    const float* x    = (const float*)d_in[0];
    const float* w    = (const float*)d_in[1];
    const int*   erow = (const int*)d_in[2];
    const int*   ecol = (const int*)d_in[3];
    const float* eval = (const float*)d_in[4];
    float* out = (float*)d_out;

    // ws layout: [0, 102.4 MB) xw fp32; then 128 KiB swizzled bf16 W
    float* xw = (float*)d_ws;
    unsigned short* wsw =
        (unsigned short*)((char*)d_ws + (size_t)N_NODES * D * sizeof(float));

    const int vec4_out = N_NODES * D / 4;  // 6,400,000 float4s

    zero_out_k<<<vec4_out / 256, 256, 0, stream>>>(out);          // 25000 blocks
    convert_w_k<<<(D * D) / 256, 256, 0, stream>>>(w, wsw);        // 256 blocks
    gemm_xw_k<<<(N_NODES + 63) / 64, 256, 0, stream>>>(x, wsw, xw); // 1563 blocks
    scatter_k<<<N_EDGES / 4, 256, 0, stream>>>(xw, erow, ecol, eval, out); // 800k blocks
    relu_k<<<vec4_out / 256, 256, 0, stream>>>(out);               // 25000 blocks
}

// Round 2
// 1097.482 us; speedup vs baseline: 9.8586x; 9.8586x over previous
//
#include <hip/hip_runtime.h>
#include <hip/hip_bf16.h>

#define N_NODES 100000
#define N_EDGES 3200000
#define D 256

typedef __attribute__((ext_vector_type(8))) short short8;   // 8 bf16 (4 VGPRs)
typedef __attribute__((ext_vector_type(4))) float floatx4;  // MFMA C/D

__device__ __forceinline__ unsigned short f32_to_bf16_rne(float f) {
    unsigned int u = __float_as_uint(f);
    u += 0x7FFFu + ((u >> 16) & 1u);   // round-to-nearest-even
    return (unsigned short)(u >> 16);
}

__device__ __forceinline__ float bf16_bits_to_f32(unsigned short b) {
    return __uint_as_float(((unsigned int)b) << 16);
}

// ---------------- W (fp32 [K=256][N=256]) -> bf16, MFMA-B-fragment order -----
// layout: t = ((ntile*8 + kstep)*64 + lane)*8 + j
//   value = W[k = kstep*32 + (lane>>4)*8 + j][n = ntile*16 + (lane&15)]
__global__ __launch_bounds__(256) void convert_w_k(const float* __restrict__ w,
                                                   unsigned short* __restrict__ wsw) {
    int t = blockIdx.x * 256 + threadIdx.x;      // 0..65535
    int j     = t & 7;
    int lane  = (t >> 3) & 63;
    int kstep = (t >> 9) & 7;
    int ntile = t >> 12;
    int k = kstep * 32 + (lane >> 4) * 8 + j;
    int n = ntile * 16 + (lane & 15);
    wsw[t] = f32_to_bf16_rne(w[k * D + n]);
}

// ---------------- xw = x @ W, bf16 MFMA 16x16x32, output bf16 ----------------
__global__ __launch_bounds__(256) void gemm_xw_k(const float* __restrict__ x,
                                                 const unsigned short* __restrict__ wsw,
                                                 unsigned short* __restrict__ xwb) {
    __shared__ uint4 wlds[8192];  // 128 KiB swizzled bf16 W
    const int tid = threadIdx.x;
#pragma unroll
    for (int i = 0; i < 32; ++i) {
        int idx = i * 256 + tid;
        wlds[idx] = ((const uint4*)wsw)[idx];
    }
    __syncthreads();

    const int lane = tid & 63;
    const int wave = tid >> 6;
    const int q    = lane >> 4;
    const int ml   = lane & 15;
    const long rowBase = (long)blockIdx.x * 64 + wave * 16;
    long arow = rowBase + ml;            // row this lane loads for the A frag
    if (arow >= N_NODES) arow = 0;       // clamp; stores masked below
    const float* xr = x + arow * (long)D;

    floatx4 acc[16];
#pragma unroll
    for (int i = 0; i < 16; ++i) acc[i] = (floatx4){0.f, 0.f, 0.f, 0.f};

    const short8* wfrag = (const short8*)wlds;

#pragma unroll
    for (int ks = 0; ks < 8; ++ks) {
        const float4 a0 = *(const float4*)(xr + ks * 32 + q * 8);
        const float4 a1 = *(const float4*)(xr + ks * 32 + q * 8 + 4);
        short8 af;
        af[0] = (short)f32_to_bf16_rne(a0.x);
        af[1] = (short)f32_to_bf16_rne(a0.y);
        af[2] = (short)f32_to_bf16_rne(a0.z);
        af[3] = (short)f32_to_bf16_rne(a0.w);
        af[4] = (short)f32_to_bf16_rne(a1.x);
        af[5] = (short)f32_to_bf16_rne(a1.y);
        af[6] = (short)f32_to_bf16_rne(a1.z);
        af[7] = (short)f32_to_bf16_rne(a1.w);
#pragma unroll
        for (int nt = 0; nt < 16; ++nt) {
            acc[nt] = __builtin_amdgcn_mfma_f32_16x16x32_bf16(
                af, wfrag[(nt * 8 + ks) * 64 + lane], acc[nt], 0, 0, 0);
        }
    }

    // C/D layout: col = nt*16 + (lane&15), row = rowBase + q*4 + r
#pragma unroll
    for (int nt = 0; nt < 16; ++nt) {
#pragma unroll
        for (int r = 0; r < 4; ++r) {
            long orow = rowBase + q * 4 + r;
            if (orow < N_NODES)
                xwb[orow * (long)D + nt * 16 + ml] = f32_to_bf16_rne(acc[nt][r]);
        }
    }
}

// ---------------- counting sort: histogram ----------------------------------
__global__ __launch_bounds__(256) void zero_counts_k(int* __restrict__ counts) {
    int i = blockIdx.x * 256 + threadIdx.x;
    if (i < N_NODES) counts[i] = 0;
}

__global__ __launch_bounds__(256) void hist_k(const int* __restrict__ erow,
                                              int* __restrict__ counts) {
    int e = blockIdx.x * 256 + threadIdx.x;
    if (e < N_EDGES) atomicAdd(&counts[erow[e]], 1);
}

// ---------------- single-block exclusive scan over 100000 counts -------------
// 1024 threads x 98 items = 100352 coverage; writes offsets[0..N_NODES] and
// cursor[0..N_NODES-1] (= offsets copy used as fill cursors).
#define SCAN_ITEMS 98
__global__ __launch_bounds__(1024) void scan_k(const int* __restrict__ counts,
                                               int* __restrict__ offsets,
                                               int* __restrict__ cursor) {
    __shared__ int sums[1024];
    const int tid = threadIdx.x;
    const int base = tid * SCAN_ITEMS;

    int s = 0;
    for (int i = 0; i < SCAN_ITEMS; ++i) {
        int idx = base + i;
        if (idx < N_NODES) s += counts[idx];
    }
    sums[tid] = s;
    __syncthreads();
    for (int o = 1; o < 1024; o <<= 1) {
        int v = (tid >= o) ? sums[tid - o] : 0;
        __syncthreads();
        sums[tid] += v;
        __syncthreads();
    }
    int running = sums[tid] - s;  // exclusive base for this thread's segment
    for (int i = 0; i < SCAN_ITEMS; ++i) {
        int idx = base + i;
        if (idx <= N_NODES) offsets[idx] = running;
        if (idx < N_NODES) {
            cursor[idx] = running;
            running += counts[idx];
        }
    }
}

// ---------------- fill sorted (col, val) pairs -------------------------------
__global__ __launch_bounds__(256) void fill_k(const int* __restrict__ erow,
                                              const int* __restrict__ ecol,
                                              const float* __restrict__ eval,
                                              int* __restrict__ cursor,
                                              int2* __restrict__ cv) {
    int e = blockIdx.x * 256 + threadIdx.x;
    if (e >= N_EDGES) return;
    int r = erow[e];
    int pos = atomicAdd(&cursor[r], 1);
    cv[pos] = make_int2(ecol[e], __float_as_int(eval[e]));
}

// ---------------- segment reduce: out[r] = relu(sum v * xwb[c]) --------------
// one wave per node; chunked coalesced edge loads + shfl broadcast;
// gather = 512 B coalesced bf16 row (8 B/lane); fp32 accumulate in registers.
__global__ __launch_bounds__(256) void aggregate_k(const unsigned short* __restrict__ xwb,
                                                   const int* __restrict__ offsets,
                                                   const int2* __restrict__ cv,
                                                   float* __restrict__ out) {
    const int wave = threadIdx.x >> 6;
    const int lane = threadIdx.x & 63;
    const int r = blockIdx.x * 4 + wave;
    if (r >= N_NODES) return;

    const int start = offsets[r];
    const int end   = offsets[r + 1];

    float4 acc = make_float4(0.f, 0.f, 0.f, 0.f);

    for (int jb = start; jb < end; jb += 64) {
        int j = jb + lane;
        int c = 0;
        float v = 0.f;
        if (j < end) {
            int2 e = cv[j];
            c = e.x;
            v = __int_as_float(e.y);
        }
        const int cnt = min(64, end - jb);
        for (int t = 0; t < cnt; ++t) {
            const int   bc = __shfl(c, t);
            const float bv = __shfl(v, t);
            const ushort4 u = ((const ushort4*)(xwb + (long)bc * D))[lane];
            acc.x += bv * bf16_bits_to_f32(u.x);
            acc.y += bv * bf16_bits_to_f32(u.y);
            acc.z += bv * bf16_bits_to_f32(u.z);
            acc.w += bv * bf16_bits_to_f32(u.w);
        }
    }

    acc.x = fmaxf(acc.x, 0.f);
    acc.y = fmaxf(acc.y, 0.f);
    acc.z = fmaxf(acc.z, 0.f);
    acc.w = fmaxf(acc.w, 0.f);
    ((float4*)(out + (long)r * D))[lane] = acc;
}

extern "C" void kernel_launch(void* const* d_in, const int* in_sizes, int n_in,
                              void* d_out, int out_size, void* d_ws, size_t ws_size,
                              hipStream_t stream) {
    const float* x    = (const float*)d_in[0];
    const float* w    = (const float*)d_in[1];
    const int*   erow = (const int*)d_in[2];
    const int*   ecol = (const int*)d_in[3];
    const float* eval = (const float*)d_in[4];
    float* out = (float*)d_out;

    // ---- workspace layout (all 256B-aligned) ----
    char* p = (char*)d_ws;
    auto align = [](size_t v) { return (v + 255) & ~(size_t)255; };

    unsigned short* xwb = (unsigned short*)p;                 // 51.2 MB
    p += align((size_t)N_NODES * D * sizeof(unsigned short));
    unsigned short* wsw = (unsigned short*)p;                 // 128 KiB
    p += align((size_t)D * D * sizeof(unsigned short));
    int* counts = (int*)p;                                    // 400 KB
    p += align((size_t)N_NODES * sizeof(int));
    int* offsets = (int*)p;                                   // 400 KB
    p += align((size_t)(N_NODES + 1) * sizeof(int));
    int* cursor = (int*)p;                                    // 400 KB
    p += align((size_t)N_NODES * sizeof(int));
    int2* cv = (int2*)p;                                      // 25.6 MB
    p += align((size_t)N_EDGES * sizeof(int2));

    convert_w_k<<<(D * D) / 256, 256, 0, stream>>>(w, wsw);
    gemm_xw_k<<<(N_NODES + 63) / 64, 256, 0, stream>>>(x, wsw, xwb);
    zero_counts_k<<<(N_NODES + 255) / 256, 256, 0, stream>>>(counts);
    hist_k<<<(N_EDGES + 255) / 256, 256, 0, stream>>>(erow, counts);
    scan_k<<<1, 1024, 0, stream>>>(counts, offsets, cursor);
    fill_k<<<(N_EDGES + 255) / 256, 256, 0, stream>>>(erow, ecol, eval, cursor, cv);
    aggregate_k<<<(N_NODES + 3) / 4, 256, 0, stream>>>(xwb, offsets, cv, out);
}

// Round 3
// 629.431 us; speedup vs baseline: 17.1896x; 1.7436x over previous
//
#include <hip/hip_runtime.h>
#include <hip/hip_bf16.h>

#define N_NODES 100000
#define N_EDGES 3200000
#define D 256
#define NB 196        // coarse buckets = rows >> 9
#define RPB 512       // rows per bucket
#define FILL_CH 8192  // edges per block in bin/hist kernels
#define NBLK_E ((N_EDGES + FILL_CH - 1) / FILL_CH)  // 391

typedef __attribute__((ext_vector_type(8))) short short8;   // 8 bf16 (4 VGPRs)
typedef __attribute__((ext_vector_type(4))) float floatx4;  // MFMA C/D

__device__ __forceinline__ unsigned short f32_to_bf16_rne(float f) {
    unsigned int u = __float_as_uint(f);
    u += 0x7FFFu + ((u >> 16) & 1u);
    return (unsigned short)(u >> 16);
}
__device__ __forceinline__ float bf16_bits_to_f32(unsigned short b) {
    return __uint_as_float(((unsigned int)b) << 16);
}
__device__ __forceinline__ float blo(unsigned int x) { return __uint_as_float(x << 16); }
__device__ __forceinline__ float bhi(unsigned int x) { return __uint_as_float(x & 0xFFFF0000u); }

// ---------------- W (fp32 [K][N]) -> bf16 MFMA-B-fragment order --------------
__global__ __launch_bounds__(256) void convert_w_k(const float* __restrict__ w,
                                                   unsigned short* __restrict__ wsw) {
    int t = blockIdx.x * 256 + threadIdx.x;
    int j     = t & 7;
    int lane  = (t >> 3) & 63;
    int kstep = (t >> 9) & 7;
    int ntile = t >> 12;
    int k = kstep * 32 + (lane >> 4) * 8 + j;
    int n = ntile * 16 + (lane & 15);
    wsw[t] = f32_to_bf16_rne(w[k * D + n]);
}

// ---------------- xw = x @ W (bf16 MFMA), output bf16 ------------------------
__global__ __launch_bounds__(256) void gemm_xw_k(const float* __restrict__ x,
                                                 const unsigned short* __restrict__ wsw,
                                                 unsigned short* __restrict__ xwb) {
    __shared__ uint4 wlds[8192];  // 128 KiB swizzled bf16 W
    const int tid = threadIdx.x;
#pragma unroll
    for (int i = 0; i < 32; ++i) {
        int idx = i * 256 + tid;
        wlds[idx] = ((const uint4*)wsw)[idx];
    }
    __syncthreads();

    const int lane = tid & 63;
    const int wave = tid >> 6;
    const int q    = lane >> 4;
    const int ml   = lane & 15;
    const long rowBase = (long)blockIdx.x * 64 + wave * 16;
    long arow = rowBase + ml;
    if (arow >= N_NODES) arow = 0;
    const float* xr = x + arow * (long)D;

    floatx4 acc[16];
#pragma unroll
    for (int i = 0; i < 16; ++i) acc[i] = (floatx4){0.f, 0.f, 0.f, 0.f};

    const short8* wfrag = (const short8*)wlds;

#pragma unroll
    for (int ks = 0; ks < 8; ++ks) {
        const float4 a0 = *(const float4*)(xr + ks * 32 + q * 8);
        const float4 a1 = *(const float4*)(xr + ks * 32 + q * 8 + 4);
        short8 af;
        af[0] = (short)f32_to_bf16_rne(a0.x);
        af[1] = (short)f32_to_bf16_rne(a0.y);
        af[2] = (short)f32_to_bf16_rne(a0.z);
        af[3] = (short)f32_to_bf16_rne(a0.w);
        af[4] = (short)f32_to_bf16_rne(a1.x);
        af[5] = (short)f32_to_bf16_rne(a1.y);
        af[6] = (short)f32_to_bf16_rne(a1.z);
        af[7] = (short)f32_to_bf16_rne(a1.w);
#pragma unroll
        for (int nt = 0; nt < 16; ++nt) {
            acc[nt] = __builtin_amdgcn_mfma_f32_16x16x32_bf16(
                af, wfrag[(nt * 8 + ks) * 64 + lane], acc[nt], 0, 0, 0);
        }
    }

#pragma unroll
    for (int nt = 0; nt < 16; ++nt) {
#pragma unroll
        for (int r = 0; r < 4; ++r) {
            long orow = rowBase + q * 4 + r;
            if (orow < N_NODES)
                xwb[orow * (long)D + nt * 16 + ml] = f32_to_bf16_rne(acc[nt][r]);
        }
    }
}

// ---------------- zero the 196 bucket counters -------------------------------
__global__ __launch_bounds__(256) void zero_counts_k(int* __restrict__ counts) {
    int t = threadIdx.x;
    if (t < NB) counts[t] = 0;
}

// ---------------- coarse-bucket histogram (LDS-aggregated) -------------------
__global__ __launch_bounds__(256) void bhist_k(const int* __restrict__ erow,
                                               int* __restrict__ counts) {
    __shared__ int h[NB];
    const int tid = threadIdx.x;
    if (tid < NB) h[tid] = 0;
    __syncthreads();
    const int s = blockIdx.x * FILL_CH;
    const int e = min(s + FILL_CH, N_EDGES);
    for (int i = s + tid; i < e; i += 256) atomicAdd(&h[erow[i] >> 9], 1);
    __syncthreads();
    if (tid < NB && h[tid] > 0) atomicAdd(&counts[tid], h[tid]);
}

// ---------------- scan 196 bucket counts (1 block) ---------------------------
__global__ __launch_bounds__(256) void bscan_k(const int* __restrict__ counts,
                                               int* __restrict__ bbase,
                                               int* __restrict__ bcursor) {
    __shared__ int sc[256];
    const int t = threadIdx.x;
    int v = (t < NB) ? counts[t] : 0;
    sc[t] = v;
    __syncthreads();
    for (int o = 1; o < 256; o <<= 1) {
        int add = (t >= o) ? sc[t - o] : 0;
        __syncthreads();
        sc[t] += add;
        __syncthreads();
    }
    int excl = sc[t] - v;
    if (t < NB) { bbase[t] = excl; bcursor[t] = excl; }
    if (t == NB - 1) bbase[NB] = sc[t];
}

// ---------------- bin edges into coarse buckets ------------------------------
// cvb: packed (row_local<<17 | col); vb: bf16 edge value.
__global__ __launch_bounds__(256) void binfill_k(const int* __restrict__ erow,
                                                 const int* __restrict__ ecol,
                                                 const float* __restrict__ eval,
                                                 int* __restrict__ bcursor,
                                                 unsigned int* __restrict__ cvb,
                                                 unsigned short* __restrict__ vb) {
    __shared__ int h[NB];
    __shared__ int lcur[NB];
    const int tid = threadIdx.x;
    if (tid < NB) h[tid] = 0;
    __syncthreads();
    const int s = blockIdx.x * FILL_CH;
    const int e = min(s + FILL_CH, N_EDGES);
    for (int i = s + tid; i < e; i += 256) atomicAdd(&h[erow[i] >> 9], 1);
    __syncthreads();
    if (tid < NB) {
        int cnt = h[tid];
        lcur[tid] = (cnt > 0) ? atomicAdd(&bcursor[tid], cnt) : 0;
    }
    __syncthreads();
    for (int i = s + tid; i < e; i += 256) {
        int r = erow[i];
        int b = r >> 9;
        int pos = atomicAdd(&lcur[b], 1);
        cvb[pos] = ((unsigned int)(r & (RPB - 1)) << 17) | (unsigned int)ecol[i];
        vb[pos]  = f32_to_bf16_rne(eval[i]);
    }
}

// ---------------- per-bucket counting sort to full row order -----------------
// one block per bucket; scatter target is an L2-resident ~100KB region.
__global__ __launch_bounds__(256) void bsort_k(const int* __restrict__ bbase,
                                               const unsigned int* __restrict__ cvb,
                                               const unsigned short* __restrict__ vb,
                                               int* __restrict__ offsets,
                                               unsigned int* __restrict__ cs,
                                               unsigned short* __restrict__ vs) {
    __shared__ int hist[RPB];
    __shared__ int cur[RPB];
    __shared__ int psc[256];
    const int t = threadIdx.x;
    const int b = blockIdx.x;
    const int base = bbase[b];
    const int endp = bbase[b + 1];

    hist[t] = 0;
    hist[t + 256] = 0;
    __syncthreads();
    for (int i = base + t; i < endp; i += 256)
        atomicAdd(&hist[cvb[i] >> 17], 1);
    __syncthreads();

    // scan 512 via 256 pair-sums
    int p = hist[2 * t] + hist[2 * t + 1];
    psc[t] = p;
    __syncthreads();
    for (int o = 1; o < 256; o <<= 1) {
        int add = (t >= o) ? psc[t - o] : 0;
        __syncthreads();
        psc[t] += add;
        __syncthreads();
    }
    int pe = psc[t] - p;  // exclusive pair base
    cur[2 * t]     = pe;
    cur[2 * t + 1] = pe + hist[2 * t];
    __syncthreads();

    // global row offsets (before cursors are consumed)
#pragma unroll
    for (int k = 0; k < 2; ++k) {
        int rl = t + k * 256;
        int r = (b << 9) + rl;
        if (r < N_NODES) offsets[r] = base + cur[rl];
    }
    if (b == NB - 1 && t == 0) offsets[N_NODES] = endp;
    __syncthreads();

    // scatter to final sorted position
    for (int i = base + t; i < endp; i += 256) {
        unsigned int u = cvb[i];
        int rl = u >> 17;
        int pos = base + atomicAdd(&cur[rl], 1);
        cs[pos] = u & 0x1FFFFu;
        vs[pos] = vb[i];
    }
}

// ---------------- segment reduce: out[r] = relu(sum v * xwb[c]) --------------
// one wave per node; paired gathers: lanes 0-31 edge 2t, lanes 32-63 edge 2t+1,
// 16B/lane dwordx4; fp32 accumulate; shfl epilogue.
__global__ __launch_bounds__(256) void aggregate_k(const unsigned short* __restrict__ xwb,
                                                   const int* __restrict__ offsets,
                                                   const unsigned int* __restrict__ cs,
                                                   const unsigned short* __restrict__ vs,
                                                   float* __restrict__ out) {
    const int wave = threadIdx.x >> 6;
    const int lane = threadIdx.x & 63;
    const int r = blockIdx.x * 4 + wave;
    if (r >= N_NODES) return;

    const int start = offsets[r];
    const int end   = offsets[r + 1];
    const int half  = lane >> 5;   // 0: even edges, 1: odd edges
    const int hl    = lane & 31;

    float acc[8];
#pragma unroll
    for (int k = 0; k < 8; ++k) acc[k] = 0.f;

    for (int jb = start; jb < end; jb += 64) {
        int j = jb + lane;
        unsigned int c = 0;
        float v = 0.f;
        if (j < end) {
            c = cs[j];
            v = bf16_bits_to_f32(vs[j]);
        }
        const int cnt = min(64, end - jb);
        const int pairs = (cnt + 1) >> 1;
        for (int t = 0; t < pairs; ++t) {
            int src = 2 * t + half;
            int srcc = min(src, cnt - 1);
            unsigned int bc = __shfl(c, srcc);
            float bv = __shfl(v, srcc);
            if (src >= cnt) bv = 0.f;
            const uint4 q = ((const uint4*)(xwb + (size_t)bc * D))[hl];
            acc[0] += bv * blo(q.x);
            acc[1] += bv * bhi(q.x);
            acc[2] += bv * blo(q.y);
            acc[3] += bv * bhi(q.y);
            acc[4] += bv * blo(q.z);
            acc[5] += bv * bhi(q.z);
            acc[6] += bv * blo(q.w);
            acc[7] += bv * bhi(q.w);
        }
    }

    // combine even/odd halves (lane l and l^32 hold the same columns)
#pragma unroll
    for (int k = 0; k < 8; ++k) acc[k] += __shfl_xor(acc[k], 32);

    // redistribute: lane l writes cols 4l..4l+3 (source lane l>>1)
    const int s = lane >> 1;
    const int par = lane & 1;
    float4 o;
    {
        float a0 = __shfl(acc[0], s), b0 = __shfl(acc[4], s);
        float a1 = __shfl(acc[1], s), b1 = __shfl(acc[5], s);
        float a2 = __shfl(acc[2], s), b2 = __shfl(acc[6], s);
        float a3 = __shfl(acc[3], s), b3 = __shfl(acc[7], s);
        o.x = par ? b0 : a0;
        o.y = par ? b1 : a1;
        o.z = par ? b2 : a2;
        o.w = par ? b3 : a3;
    }
    o.x = fmaxf(o.x, 0.f);
    o.y = fmaxf(o.y, 0.f);
    o.z = fmaxf(o.z, 0.f);
    o.w = fmaxf(o.w, 0.f);
    ((float4*)(out + (size_t)r * D))[lane] = o;
}

extern "C" void kernel_launch(void* const* d_in, const int* in_sizes, int n_in,
                              void* d_out, int out_size, void* d_ws, size_t ws_size,
                              hipStream_t stream) {
    const float* x    = (const float*)d_in[0];
    const float* w    = (const float*)d_in[1];
    const int*   erow = (const int*)d_in[2];
    const int*   ecol = (const int*)d_in[3];
    const float* eval = (const float*)d_in[4];
    float* out = (float*)d_out;

    // ---- workspace layout (~90.4 MB) ----
    char* p = (char*)d_ws;
    auto align = [](size_t v) { return (v + 255) & ~(size_t)255; };

    unsigned short* xwb = (unsigned short*)p;                  // 51.2 MB
    p += align((size_t)N_NODES * D * sizeof(unsigned short));
    unsigned short* wsw = (unsigned short*)p;                  // 128 KiB
    p += align((size_t)D * D * sizeof(unsigned short));
    int* bcounts = (int*)p;  p += align((size_t)NB * sizeof(int));
    int* bbase   = (int*)p;  p += align((size_t)(NB + 1) * sizeof(int));
    int* bcursor = (int*)p;  p += align((size_t)NB * sizeof(int));
    unsigned int*   cvb = (unsigned int*)p;    p += align((size_t)N_EDGES * 4);  // 12.8 MB
    unsigned short* vb  = (unsigned short*)p;  p += align((size_t)N_EDGES * 2);  // 6.4 MB
    unsigned int*   cs  = (unsigned int*)p;    p += align((size_t)N_EDGES * 4);  // 12.8 MB
    unsigned short* vs  = (unsigned short*)p;  p += align((size_t)N_EDGES * 2);  // 6.4 MB
    int* offsets = (int*)p;  p += align((size_t)(N_NODES + 1) * sizeof(int));    // 400 KB

    convert_w_k<<<(D * D) / 256, 256, 0, stream>>>(w, wsw);
    gemm_xw_k<<<(N_NODES + 63) / 64, 256, 0, stream>>>(x, wsw, xwb);
    zero_counts_k<<<1, 256, 0, stream>>>(bcounts);
    bhist_k<<<NBLK_E, 256, 0, stream>>>(erow, bcounts);
    bscan_k<<<1, 256, 0, stream>>>(bcounts, bbase, bcursor);
    binfill_k<<<NBLK_E, 256, 0, stream>>>(erow, ecol, eval, bcursor, cvb, vb);
    bsort_k<<<NB, 256, 0, stream>>>(bbase, cvb, vb, offsets, cs, vs);
    aggregate_k<<<(N_NODES + 3) / 4, 256, 0, stream>>>(xwb, offsets, cs, vs, out);
}

// Round 4
// 610.435 us; speedup vs baseline: 17.7245x; 1.0311x over previous
//
#include <hip/hip_runtime.h>
#include <hip/hip_bf16.h>

#define N_NODES 100000
#define N_EDGES 3200000
#define D 256
#define RSH 7
#define RPB 128                                  // rows per bucket = 1<<RSH
#define NB ((N_NODES + RPB - 1) / RPB)           // 782 coarse buckets
#define FILL_CH 8192                             // edges per block in bin/hist
#define NBLK_E ((N_EDGES + FILL_CH - 1) / FILL_CH)  // 391

typedef __attribute__((ext_vector_type(8))) short short8;   // 8 bf16 (4 VGPRs)
typedef __attribute__((ext_vector_type(4))) float floatx4;  // MFMA C/D

__device__ __forceinline__ unsigned short f32_to_bf16_rne(float f) {
    unsigned int u = __float_as_uint(f);
    u += 0x7FFFu + ((u >> 16) & 1u);
    return (unsigned short)(u >> 16);
}
__device__ __forceinline__ float bf16_bits_to_f32(unsigned short b) {
    return __uint_as_float(((unsigned int)b) << 16);
}
__device__ __forceinline__ float blo(unsigned int x) { return __uint_as_float(x << 16); }
__device__ __forceinline__ float bhi(unsigned int x) { return __uint_as_float(x & 0xFFFF0000u); }

// ---------------- W (fp32 [K][N]) -> bf16 MFMA-B-fragment order --------------
__global__ __launch_bounds__(256) void convert_w_k(const float* __restrict__ w,
                                                   unsigned short* __restrict__ wsw) {
    int t = blockIdx.x * 256 + threadIdx.x;
    int j     = t & 7;
    int lane  = (t >> 3) & 63;
    int kstep = (t >> 9) & 7;
    int ntile = t >> 12;
    int k = kstep * 32 + (lane >> 4) * 8 + j;
    int n = ntile * 16 + (lane & 15);
    wsw[t] = f32_to_bf16_rne(w[k * D + n]);
}

// ---------------- xw = x @ W (bf16 MFMA), output bf16 ------------------------
__global__ __launch_bounds__(256) void gemm_xw_k(const float* __restrict__ x,
                                                 const unsigned short* __restrict__ wsw,
                                                 unsigned short* __restrict__ xwb) {
    __shared__ uint4 wlds[8192];  // 128 KiB swizzled bf16 W
    const int tid = threadIdx.x;
#pragma unroll
    for (int i = 0; i < 32; ++i) {
        int idx = i * 256 + tid;
        wlds[idx] = ((const uint4*)wsw)[idx];
    }
    __syncthreads();

    const int lane = tid & 63;
    const int wave = tid >> 6;
    const int q    = lane >> 4;
    const int ml   = lane & 15;
    const long rowBase = (long)blockIdx.x * 64 + wave * 16;
    long arow = rowBase + ml;
    if (arow >= N_NODES) arow = 0;
    const float* xr = x + arow * (long)D;

    floatx4 acc[16];
#pragma unroll
    for (int i = 0; i < 16; ++i) acc[i] = (floatx4){0.f, 0.f, 0.f, 0.f};

    const short8* wfrag = (const short8*)wlds;

#pragma unroll
    for (int ks = 0; ks < 8; ++ks) {
        const float4 a0 = *(const float4*)(xr + ks * 32 + q * 8);
        const float4 a1 = *(const float4*)(xr + ks * 32 + q * 8 + 4);
        short8 af;
        af[0] = (short)f32_to_bf16_rne(a0.x);
        af[1] = (short)f32_to_bf16_rne(a0.y);
        af[2] = (short)f32_to_bf16_rne(a0.z);
        af[3] = (short)f32_to_bf16_rne(a0.w);
        af[4] = (short)f32_to_bf16_rne(a1.x);
        af[5] = (short)f32_to_bf16_rne(a1.y);
        af[6] = (short)f32_to_bf16_rne(a1.z);
        af[7] = (short)f32_to_bf16_rne(a1.w);
#pragma unroll
        for (int nt = 0; nt < 16; ++nt) {
            acc[nt] = __builtin_amdgcn_mfma_f32_16x16x32_bf16(
                af, wfrag[(nt * 8 + ks) * 64 + lane], acc[nt], 0, 0, 0);
        }
    }

#pragma unroll
    for (int nt = 0; nt < 16; ++nt) {
#pragma unroll
        for (int r = 0; r < 4; ++r) {
            long orow = rowBase + q * 4 + r;
            if (orow < N_NODES)
                xwb[orow * (long)D + nt * 16 + ml] = f32_to_bf16_rne(acc[nt][r]);
        }
    }
}

// ---------------- zero the bucket counters -----------------------------------
__global__ __launch_bounds__(256) void zero_counts_k(int* __restrict__ counts) {
    int i = blockIdx.x * 256 + threadIdx.x;
    if (i < NB) counts[i] = 0;
}

// ---------------- coarse-bucket histogram (LDS-aggregated) -------------------
__global__ __launch_bounds__(256) void bhist_k(const int* __restrict__ erow,
                                               int* __restrict__ counts) {
    __shared__ int h[NB];
    const int tid = threadIdx.x;
    for (int i = tid; i < NB; i += 256) h[i] = 0;
    __syncthreads();
    const int s = blockIdx.x * FILL_CH;
    const int e = min(s + FILL_CH, N_EDGES);
    for (int i = s + tid; i < e; i += 256) atomicAdd(&h[erow[i] >> RSH], 1);
    __syncthreads();
    for (int i = tid; i < NB; i += 256)
        if (h[i] > 0) atomicAdd(&counts[i], h[i]);
}

// ---------------- scan NB bucket counts (1 block of 1024) --------------------
__global__ __launch_bounds__(1024) void bscan_k(const int* __restrict__ counts,
                                                int* __restrict__ bbase,
                                                int* __restrict__ bcursor) {
    __shared__ int sc[1024];
    const int t = threadIdx.x;
    int v = (t < NB) ? counts[t] : 0;
    sc[t] = v;
    __syncthreads();
    for (int o = 1; o < 1024; o <<= 1) {
        int add = (t >= o) ? sc[t - o] : 0;
        __syncthreads();
        sc[t] += add;
        __syncthreads();
    }
    int excl = sc[t] - v;
    if (t < NB) { bbase[t] = excl; bcursor[t] = excl; }
    if (t == NB - 1) bbase[NB] = sc[t];
}

// ---------------- bin edges into coarse buckets (packed u64 records) ---------
// rec = row_local<<33 | val_bf16<<17 | col
__global__ __launch_bounds__(256) void binfill_k(const int* __restrict__ erow,
                                                 const int* __restrict__ ecol,
                                                 const float* __restrict__ eval,
                                                 int* __restrict__ bcursor,
                                                 unsigned long long* __restrict__ recs) {
    __shared__ int h[NB];
    __shared__ int lcur[NB];
    const int tid = threadIdx.x;
    for (int i = tid; i < NB; i += 256) h[i] = 0;
    __syncthreads();
    const int s = blockIdx.x * FILL_CH;
    const int e = min(s + FILL_CH, N_EDGES);
    for (int i = s + tid; i < e; i += 256) atomicAdd(&h[erow[i] >> RSH], 1);
    __syncthreads();
    for (int i = tid; i < NB; i += 256) {
        int cnt = h[i];
        lcur[i] = (cnt > 0) ? atomicAdd(&bcursor[i], cnt) : 0;
    }
    __syncthreads();
    for (int i = s + tid; i < e; i += 256) {
        int r = erow[i];
        int b = r >> RSH;
        int pos = atomicAdd(&lcur[b], 1);
        unsigned long long rec =
            ((unsigned long long)(r & (RPB - 1)) << 33) |
            ((unsigned long long)f32_to_bf16_rne(eval[i]) << 17) |
            (unsigned int)ecol[i];
        recs[pos] = rec;
    }
}

// ---------------- per-bucket counting sort to full row order -----------------
// one block per bucket (782 blocks, ~3/CU); scatter region ~33KB L2-resident.
__global__ __launch_bounds__(256) void bsort_k(const int* __restrict__ bbase,
                                               const unsigned long long* __restrict__ recs,
                                               int* __restrict__ offsets,
                                               unsigned int* __restrict__ cs,
                                               unsigned short* __restrict__ vs) {
    __shared__ int hist[RPB];
    __shared__ int cur[RPB];
    __shared__ int sc[RPB];
    const int t = threadIdx.x;
    const int b = blockIdx.x;
    const int base = bbase[b];
    const int endp = bbase[b + 1];

    if (t < RPB) hist[t] = 0;
    __syncthreads();
    for (int i = base + t; i < endp; i += 256)
        atomicAdd(&hist[(int)(recs[i] >> 33)], 1);
    __syncthreads();

    if (t < RPB) sc[t] = hist[t];
    __syncthreads();
    for (int o = 1; o < RPB; o <<= 1) {
        int add = (t >= o && t < RPB) ? sc[t - o] : 0;
        __syncthreads();
        if (t < RPB) sc[t] += add;
        __syncthreads();
    }
    if (t < RPB) {
        int excl = sc[t] - hist[t];
        cur[t] = excl;
        int r = (b << RSH) + t;
        if (r <= N_NODES) offsets[r] = base + excl;   // r==N_NODES covered by last bucket
    }
    __syncthreads();

    for (int i = base + t; i < endp; i += 256) {
        unsigned long long rec = recs[i];
        int rl = (int)(rec >> 33);
        int pos = base + atomicAdd(&cur[rl], 1);
        cs[pos] = (unsigned int)(rec & 0x1FFFFu);
        vs[pos] = (unsigned short)((rec >> 17) & 0xFFFFu);
    }
}

// ---------------- segment reduce: out[r] = relu(sum v * xwb[c]) --------------
// one wave per node; paired gathers (2 edges / load instr), unrolled x4 so
// 4 independent uint4 gathers are in flight per wave (VGPR ~50, 8 waves/SIMD).
__global__ __launch_bounds__(256) void aggregate_k(const unsigned short* __restrict__ xwb,
                                                   const int* __restrict__ offsets,
                                                   const unsigned int* __restrict__ cs,
                                                   const unsigned short* __restrict__ vs,
                                                   float* __restrict__ out) {
    const int wave = threadIdx.x >> 6;
    const int lane = threadIdx.x & 63;
    const int r = blockIdx.x * 4 + wave;
    if (r >= N_NODES) return;

    const int start = offsets[r];
    const int end   = offsets[r + 1];
    const int half  = lane >> 5;
    const int hl    = lane & 31;

    float acc[8];
#pragma unroll
    for (int k = 0; k < 8; ++k) acc[k] = 0.f;

    for (int jb = start; jb < end; jb += 64) {
        int j = jb + lane;
        unsigned int c = 0;
        float v = 0.f;
        if (j < end) {
            c = cs[j];
            v = bf16_bits_to_f32(vs[j]);
        }
        const int cnt = min(64, end - jb);
        const int pairs = (cnt + 1) >> 1;
        int t = 0;
        for (; t + 4 <= pairs; t += 4) {
            uint4 q0, q1, q2, q3;
            float b0, b1, b2, b3;
#define SLOT(s, qv, bv)                                                        \
            {                                                                  \
                int src = 2 * (t + (s)) + half;                                \
                int srcc = min(src, cnt - 1);                                  \
                unsigned int bc = (unsigned int)__shfl((int)c, srcc);          \
                float bb = __shfl(v, srcc);                                    \
                bv = (src < cnt) ? bb : 0.f;                                   \
                qv = ((const uint4*)(xwb + (size_t)bc * D))[hl];               \
            }
            SLOT(0, q0, b0)
            SLOT(1, q1, b1)
            SLOT(2, q2, b2)
            SLOT(3, q3, b3)
#undef SLOT
#define FMA8(qv, bv)                                                           \
            acc[0] += bv * blo(qv.x); acc[1] += bv * bhi(qv.x);                \
            acc[2] += bv * blo(qv.y); acc[3] += bv * bhi(qv.y);                \
            acc[4] += bv * blo(qv.z); acc[5] += bv * bhi(qv.z);                \
            acc[6] += bv * blo(qv.w); acc[7] += bv * bhi(qv.w);
            FMA8(q0, b0)
            FMA8(q1, b1)
            FMA8(q2, b2)
            FMA8(q3, b3)
#undef FMA8
        }
        for (; t < pairs; ++t) {
            int src = 2 * t + half;
            int srcc = min(src, cnt - 1);
            unsigned int bc = (unsigned int)__shfl((int)c, srcc);
            float bb = __shfl(v, srcc);
            float bv = (src < cnt) ? bb : 0.f;
            uint4 q = ((const uint4*)(xwb + (size_t)bc * D))[hl];
            acc[0] += bv * blo(q.x); acc[1] += bv * bhi(q.x);
            acc[2] += bv * blo(q.y); acc[3] += bv * bhi(q.y);
            acc[4] += bv * blo(q.z); acc[5] += bv * bhi(q.z);
            acc[6] += bv * blo(q.w); acc[7] += bv * bhi(q.w);
        }
    }

    // combine even/odd halves (lane l and l^32 hold the same columns)
#pragma unroll
    for (int k = 0; k < 8; ++k) acc[k] += __shfl_xor(acc[k], 32);

    // redistribute: lane l writes cols 4l..4l+3 (source lane l>>1)
    const int s = lane >> 1;
    const int par = lane & 1;
    float4 o;
    {
        float a0 = __shfl(acc[0], s), b0 = __shfl(acc[4], s);
        float a1 = __shfl(acc[1], s), b1 = __shfl(acc[5], s);
        float a2 = __shfl(acc[2], s), b2 = __shfl(acc[6], s);
        float a3 = __shfl(acc[3], s), b3 = __shfl(acc[7], s);
        o.x = par ? b0 : a0;
        o.y = par ? b1 : a1;
        o.z = par ? b2 : a2;
        o.w = par ? b3 : a3;
    }
    o.x = fmaxf(o.x, 0.f);
    o.y = fmaxf(o.y, 0.f);
    o.z = fmaxf(o.z, 0.f);
    o.w = fmaxf(o.w, 0.f);
    ((float4*)(out + (size_t)r * D))[lane] = o;
}

extern "C" void kernel_launch(void* const* d_in, const int* in_sizes, int n_in,
                              void* d_out, int out_size, void* d_ws, size_t ws_size,
                              hipStream_t stream) {
    const float* x    = (const float*)d_in[0];
    const float* w    = (const float*)d_in[1];
    const int*   erow = (const int*)d_in[2];
    const int*   ecol = (const int*)d_in[3];
    const float* eval = (const float*)d_in[4];
    float* out = (float*)d_out;

    // ---- workspace layout (~96.6 MB) ----
    char* p = (char*)d_ws;
    auto align = [](size_t v) { return (v + 255) & ~(size_t)255; };

    unsigned short* xwb = (unsigned short*)p;                  // 51.2 MB
    p += align((size_t)N_NODES * D * sizeof(unsigned short));
    unsigned short* wsw = (unsigned short*)p;                  // 128 KiB
    p += align((size_t)D * D * sizeof(unsigned short));
    int* bcounts = (int*)p;  p += align((size_t)NB * sizeof(int));
    int* bbase   = (int*)p;  p += align((size_t)(NB + 1) * sizeof(int));
    int* bcursor = (int*)p;  p += align((size_t)NB * sizeof(int));
    unsigned long long* recs = (unsigned long long*)p;         // 25.6 MB
    p += align((size_t)N_EDGES * sizeof(unsigned long long));
    unsigned int*   cs = (unsigned int*)p;    p += align((size_t)N_EDGES * 4);  // 12.8 MB
    unsigned short* vs = (unsigned short*)p;  p += align((size_t)N_EDGES * 2);  // 6.4 MB
    int* offsets = (int*)p;  p += align((size_t)(N_NODES + 1) * sizeof(int));   // 400 KB

    convert_w_k<<<(D * D) / 256, 256, 0, stream>>>(w, wsw);
    gemm_xw_k<<<(N_NODES + 63) / 64, 256, 0, stream>>>(x, wsw, xwb);
    zero_counts_k<<<(NB + 255) / 256, 256, 0, stream>>>(bcounts);
    bhist_k<<<NBLK_E, 256, 0, stream>>>(erow, bcounts);
    bscan_k<<<1, 1024, 0, stream>>>(bcounts, bbase, bcursor);
    binfill_k<<<NBLK_E, 256, 0, stream>>>(erow, ecol, eval, bcursor, recs);
    bsort_k<<<NB, 256, 0, stream>>>(bbase, recs, offsets, cs, vs);
    aggregate_k<<<(N_NODES + 3) / 4, 256, 0, stream>>>(xwb, offsets, cs, vs, out);
}